// Round 2
// baseline (966.325 us; speedup 1.0000x reference)
//
#include <hip/hip_runtime.h>
#include <hip/hip_bf16.h>
#include <hip/hip_fp16.h>

typedef _Float16 f16;
typedef __attribute__((ext_vector_type(8))) _Float16 f16x8;
typedef __attribute__((ext_vector_type(4))) _Float16 f16x4;
typedef __attribute__((ext_vector_type(2))) _Float16 f16x2;
typedef __attribute__((ext_vector_type(4))) float f32x4;

#define AS1(p) ((const __attribute__((address_space(1))) void*)(p))
#define AS3(p) ((__attribute__((address_space(3))) void*)(p))

// ---------------- weight fp32 -> f16 conversion (concatenated) ----------------
// layout in dst (f16 elems): wq [0,196608) | wp [196608,262144) | wf1 [262144,524288) | wf2 [524288,786432)
__global__ __launch_bounds__(256) void cvt_weights(
    const float* __restrict__ wq, const float* __restrict__ wp,
    const float* __restrict__ wf1, const float* __restrict__ wf2,
    f16* __restrict__ o) {
  int i = blockIdx.x * 256 + threadIdx.x;  // grid sized exactly 786432
  float v;
  if (i < 196608)       v = wq[i];
  else if (i < 262144)  v = wp[i - 196608];
  else if (i < 524288)  v = wf1[i - 262144];
  else                  v = wf2[i - 524288];
  o[i] = (f16)v;
}

// ---------------- LayerNorm (one wave per 256-elem row) ----------------
// PART=true: write window-partitioned order; PART=false: natural row order
template<bool PART>
__global__ __launch_bounds__(256) void ln_rows(
    const float* __restrict__ x, const float* __restrict__ g,
    const float* __restrict__ b, f16* __restrict__ out) {
  const int t = blockIdx.x * 4 + (threadIdx.x >> 6);   // token row within chunk
  const int lane = threadIdx.x & 63;
  const float4 v = ((const float4*)(x + (long)t * 256))[lane];
  float s  = v.x + v.y + v.z + v.w;
  float ss = v.x*v.x + v.y*v.y + v.z*v.z + v.w*v.w;
  #pragma unroll
  for (int off = 32; off; off >>= 1) {
    s  += __shfl_xor(s, off);
    ss += __shfl_xor(ss, off);
  }
  const float mu = s * (1.0f / 256.0f);
  const float var = ss * (1.0f / 256.0f) - mu * mu;
  const float rs = rsqrtf(var + 1e-5f);
  const float4 gv = ((const float4*)g)[lane];
  const float4 bv = ((const float4*)b)[lane];
  long row;
  if (PART) {
    const int bI = t >> 12, l = t & 4095;
    const int hh = l >> 6, w2 = l & 63;
    const int wi = bI * 64 + (hh >> 3) * 8 + (w2 >> 3);
    const int n  = (hh & 7) * 8 + (w2 & 7);
    row = (long)wi * 64 + n;
  } else {
    row = t;
  }
  f16x4 o4;
  o4[0] = (f16)((v.x - mu) * rs * gv.x + bv.x);
  o4[1] = (f16)((v.y - mu) * rs * gv.y + bv.y);
  o4[2] = (f16)((v.z - mu) * rs * gv.z + bv.z);
  o4[3] = (f16)((v.w - mu) * rs * gv.w + bv.w);
  *(f16x4*)(out + row * 256 + lane * 4) = o4;
}

// ---------------- GEMM: C[M,N] = A[M,K] @ Bw[N,K]^T + bias, fused epilogues ----------------
// EPI 0: f16 out = v
// EPI 1: f32 out[window-reversed idx] = resid[idx] + v        (proj + residual)
// EPI 2: f16 out = gelu_exact(v)                              (fc1)
// EPI 3: f32 out = resid + v                                  (fc2 + residual, final)
template<int EPI, int K>
__global__ __launch_bounds__(256) void gemm_bt(
    const f16* __restrict__ A, const f16* __restrict__ Bw,
    const float* __restrict__ bias, const float* __restrict__ resid,
    f16* __restrict__ outh, float* __restrict__ outf, int N) {
  __shared__ f16 As[128 * 32];
  __shared__ f16 Bs[128 * 32];
  const int tid  = threadIdx.x;
  const int wid  = tid >> 6;
  const int lane = tid & 63;
  const int qd   = lane >> 4;       // quad 0..3
  const int l16  = lane & 15;
  const long tM = (long)blockIdx.y * 128;
  const int  tN = blockIdx.x * 128;
  const int srow = lane >> 2;       // 0..15
  const int scol = (lane & 3) * 8;  // 0,8,16,24
  const int wm = (wid >> 1) * 64;
  const int wn = (wid & 1) * 64;

  f32x4 acc[4][4];
  #pragma unroll
  for (int i = 0; i < 4; ++i)
    #pragma unroll
    for (int j = 0; j < 4; ++j) acc[i][j] = (f32x4){0.f, 0.f, 0.f, 0.f};

  for (int k0 = 0; k0 < K; k0 += 32) {
    #pragma unroll
    for (int t = 0; t < 2; ++t) {
      const int gidx = wid * 2 + t;          // 16-row group 0..7
      const int row  = gidx * 16 + srow;
      __builtin_amdgcn_global_load_lds(AS1(A + (tM + row) * K + k0 + scol),
                                       AS3(&As[gidx * 512]), 16, 0, 0);
      __builtin_amdgcn_global_load_lds(AS1(Bw + (long)(tN + row) * K + k0 + scol),
                                       AS3(&Bs[gidx * 512]), 16, 0, 0);
    }
    __syncthreads();
    f16x8 af[4], bf[4];
    #pragma unroll
    for (int i = 0; i < 4; ++i) af[i] = *(const f16x8*)&As[(wm + i * 16 + l16) * 32 + qd * 8];
    #pragma unroll
    for (int j = 0; j < 4; ++j) bf[j] = *(const f16x8*)&Bs[(wn + j * 16 + l16) * 32 + qd * 8];
    #pragma unroll
    for (int i = 0; i < 4; ++i)
      #pragma unroll
      for (int j = 0; j < 4; ++j)
        acc[i][j] = __builtin_amdgcn_mfma_f32_16x16x32_f16(af[i], bf[j], acc[i][j], 0, 0, 0);
    __syncthreads();
  }

  #pragma unroll
  for (int j = 0; j < 4; ++j) {
    const int col = tN + wn + j * 16 + l16;
    const float bb = bias[col];
    #pragma unroll
    for (int i = 0; i < 4; ++i) {
      #pragma unroll
      for (int r = 0; r < 4; ++r) {
        const long row = tM + wm + i * 16 + qd * 4 + r;
        const float v = acc[i][j][r] + bb;
        if (EPI == 0) {
          outh[row * N + col] = (f16)v;
        } else if (EPI == 1) {
          const int rw = (int)row;
          const int wi = rw >> 6, n = rw & 63;
          const int bI = wi >> 6, wloc = wi & 63;
          const int hh = (wloc >> 3) * 8 + (n >> 3);
          const int w2 = (wloc & 7) * 8 + (n & 7);
          const long off = ((long)bI * 4096 + hh * 64 + w2) * 256 + col;
          outf[off] = resid[off] + v;
        } else if (EPI == 2) {
          const float gv = 0.5f * v * (1.0f + erff(v * 0.70710678118654752f));
          outh[row * N + col] = (f16)gv;
        } else {
          const long off = row * 256 + col;
          outf[off] = resid[off] + v;
        }
      }
    }
  }
}

// ---------------- windowed attention: one wave per (window, head), lane = row n ----------------
__global__ __launch_bounds__(256) void attn_win(
    const f16* __restrict__ qkv, const float* __restrict__ bt,
    f16* __restrict__ out) {
  __shared__ f16 KV[4][2][64 * 32];   // per-wave K,V tiles (f16): 4 waves * 8KB
  const int wid = threadIdx.x >> 6, lane = threadIdx.x & 63;
  const int unit = blockIdx.x * 4 + wid;   // (window,head) unit within chunk
  const int wi = unit >> 3, h = unit & 7;
  const long base = (long)wi * 64 * 768;

  // stage K (cols 256+h*32..) and V (cols 512+h*32..) as 4B chunks, conflict-free
  #pragma unroll
  for (int i = 0; i < 16; ++i) {
    const int c = i * 64 + lane;     // 0..1023 (uint chunks; 16 per 32-elem row)
    const int row = c >> 4;
    const int cc = (c & 15) * 2;
    ((unsigned int*)KV[wid][0])[c] = *(const unsigned int*)(qkv + base + row * 768 + 256 + h * 32 + cc);
    ((unsigned int*)KV[wid][1])[c] = *(const unsigned int*)(qkv + base + row * 768 + 512 + h * 32 + cc);
  }
  __syncthreads();

  const int n = lane;
  f16x2 q2[16];
  const f16x2* qp = (const f16x2*)(qkv + base + n * 768 + h * 32);
  #pragma unroll
  for (int c = 0; c < 16; ++c) q2[c] = qp[c];

  const float scale = 0.17677669529663687f;  // 1/sqrt(32)
  float S[64];
  const f16x2* Kl = (const f16x2*)KV[wid][0];
  #pragma unroll
  for (int m = 0; m < 64; ++m) {
    float s = 0.f;
    #pragma unroll
    for (int c = 0; c < 16; ++c)
      s = __builtin_amdgcn_fdot2(q2[c], Kl[m * 16 + c], s, false);
    const int idx = ((n >> 3) - (m >> 3) + 7) * 15 + ((n & 7) - (m & 7) + 7);
    S[m] = s * scale + bt[idx * 8 + h];
  }
  float mx = S[0];
  #pragma unroll
  for (int m = 1; m < 64; ++m) mx = fmaxf(mx, S[m]);

  float O[32];
  #pragma unroll
  for (int c = 0; c < 32; ++c) O[c] = 0.f;
  float sum = 0.f;
  const f16x2* Vl = (const f16x2*)KV[wid][1];
  #pragma unroll
  for (int m = 0; m < 64; ++m) {
    const float p = __expf(S[m] - mx);
    sum += p;
    #pragma unroll
    for (int c = 0; c < 16; ++c) {
      const f16x2 vv = Vl[m * 16 + c];
      O[2 * c]     += p * (float)vv.x;
      O[2 * c + 1] += p * (float)vv.y;
    }
  }
  const float inv = 1.f / sum;
  f16x2* op = (f16x2*)(out + ((long)wi * 64 + n) * 256 + h * 32);
  #pragma unroll
  for (int c = 0; c < 16; ++c) {
    f16x2 o2;
    o2.x = (f16)(O[2 * c] * inv);
    o2.y = (f16)(O[2 * c + 1] * inv);
    op[c] = o2;
  }
}

// ---------------- launch ----------------
extern "C" void kernel_launch(void* const* d_in, const int* in_sizes, int n_in,
                              void* d_out, int out_size, void* d_ws, size_t ws_size,
                              hipStream_t stream) {
  const float* x     = (const float*)d_in[0];
  const float* g1    = (const float*)d_in[2];
  const float* b1    = (const float*)d_in[3];
  const float* wqkv  = (const float*)d_in[4];
  const float* bqkv  = (const float*)d_in[5];
  const float* btab  = (const float*)d_in[6];
  const float* wproj = (const float*)d_in[7];
  const float* bproj = (const float*)d_in[8];
  const float* g2    = (const float*)d_in[9];
  const float* b2    = (const float*)d_in[10];
  const float* wfc1  = (const float*)d_in[11];
  const float* bfc1  = (const float*)d_in[12];
  const float* wfc2  = (const float*)d_in[13];
  const float* bfc2  = (const float*)d_in[14];
  float* out = (float*)d_out;   // also serves as x1 (fp32 residual) scratch

  char* ws = (char*)d_ws;
  // weights f16: 786432 elems = 1.5 MB at ws[0, 2MB)
  f16* wgt   = (f16*)ws;
  f16* wq16  = wgt;
  f16* wp16  = wgt + 196608;
  f16* wf116 = wgt + 262144;
  f16* wf216 = wgt + 524288;

  // Pick largest per-pass image count CH with 2MB + CH*10MB <= ws_size.
  // Per-image: xn 2MB | qkv 6MB | xn2 2MB ; h (8MB) reuses xn+qkv regions.
  int CH = 1;
  for (int cand = 32; cand >= 1; cand >>= 1) {
    const size_t need = 2097152ULL + (size_t)cand * 10485760ULL;
    if (need <= ws_size) { CH = cand; break; }
  }
  const int NC = 32 / CH;

  const size_t O_xn  = 2097152ULL;
  const size_t O_qkv = O_xn + (size_t)CH * 2097152ULL;
  const size_t O_xn2 = O_qkv + (size_t)CH * 6291456ULL;
  f16* xnw  = (f16*)(ws + O_xn);    // ln1 out / attn out
  f16* qkvb = (f16*)(ws + O_qkv);
  f16* xn2  = (f16*)(ws + O_xn2);
  f16* hbuf = (f16*)(ws + O_xn);    // fc1 out: reuses xn+qkv (exactly CH*8MB)

  cvt_weights<<<3072, 256, 0, stream>>>(wqkv, wproj, wfc1, wfc2, wgt);

  const long imgElems = 4096L * 256;   // fp32 elems per image
  for (int c = 0; c < NC; ++c) {
    const float* xc  = x   + (long)c * CH * imgElems;
    float*       x1c = out + (long)c * CH * imgElems;
    ln_rows<true><<<CH * 1024, 256, 0, stream>>>(xc, g1, b1, xnw);
    gemm_bt<0, 256><<<dim3(6, CH * 32), 256, 0, stream>>>(xnw, wq16, bqkv, nullptr, qkvb, nullptr, 768);
    attn_win<<<CH * 128, 256, 0, stream>>>(qkvb, btab, xnw);
    gemm_bt<1, 256><<<dim3(2, CH * 32), 256, 0, stream>>>(xnw, wp16, bproj, xc, nullptr, x1c, 256);
    ln_rows<false><<<CH * 1024, 256, 0, stream>>>(x1c, g2, b2, xn2);
    gemm_bt<2, 256><<<dim3(8, CH * 32), 256, 0, stream>>>(xn2, wf116, bfc1, nullptr, hbuf, nullptr, 1024);
    gemm_bt<3, 1024><<<dim3(2, CH * 32), 256, 0, stream>>>(hbuf, wf216, bfc2, x1c, nullptr, x1c, 256);
  }
}

// Round 4
// 925.661 us; speedup vs baseline: 1.0439x; 1.0439x over previous
//
#include <hip/hip_runtime.h>
#include <hip/hip_bf16.h>
#include <hip/hip_fp16.h>

typedef _Float16 f16;
typedef __attribute__((ext_vector_type(8))) _Float16 f16x8;
typedef __attribute__((ext_vector_type(4))) _Float16 f16x4;
typedef __attribute__((ext_vector_type(2))) _Float16 f16x2;
typedef __attribute__((ext_vector_type(4))) float f32x4;

#define AS1(p) ((const __attribute__((address_space(1))) void*)(p))
#define AS3(p) ((__attribute__((address_space(3))) void*)(p))

// ---------------- weight fp32 -> f16 conversion (concatenated) ----------------
__global__ __launch_bounds__(256) void cvt_weights(
    const float* __restrict__ wq, const float* __restrict__ wp,
    const float* __restrict__ wf1, const float* __restrict__ wf2,
    f16* __restrict__ o) {
  int i = blockIdx.x * 256 + threadIdx.x;  // grid sized exactly 786432
  float v;
  if (i < 196608)       v = wq[i];
  else if (i < 262144)  v = wp[i - 196608];
  else if (i < 524288)  v = wf1[i - 262144];
  else                  v = wf2[i - 524288];
  o[i] = (f16)v;
}

// ---------------- LayerNorm (one wave per 256-elem row) ----------------
// PART=true: write window-partitioned order; PART=false: natural row order
template<bool PART, typename TIN>
__global__ __launch_bounds__(256) void ln_rows(
    const TIN* __restrict__ x, const float* __restrict__ g,
    const float* __restrict__ b, f16* __restrict__ out) {
  const int t = blockIdx.x * 4 + (threadIdx.x >> 6);   // token row within chunk
  const int lane = threadIdx.x & 63;
  float v0, v1, v2, v3;
  if constexpr (sizeof(TIN) == 4) {
    const float4 v = ((const float4*)(x + (long)t * 256))[lane];
    v0 = v.x; v1 = v.y; v2 = v.z; v3 = v.w;
  } else {
    const f16x4 v = ((const f16x4*)(x + (long)t * 256))[lane];
    v0 = (float)v[0]; v1 = (float)v[1]; v2 = (float)v[2]; v3 = (float)v[3];
  }
  float s  = v0 + v1 + v2 + v3;
  float ss = v0*v0 + v1*v1 + v2*v2 + v3*v3;
  #pragma unroll
  for (int off = 32; off; off >>= 1) {
    s  += __shfl_xor(s, off);
    ss += __shfl_xor(ss, off);
  }
  const float mu = s * (1.0f / 256.0f);
  const float var = ss * (1.0f / 256.0f) - mu * mu;
  const float rs = rsqrtf(var + 1e-5f);
  const float4 gv = ((const float4*)g)[lane];
  const float4 bv = ((const float4*)b)[lane];
  long row;
  if (PART) {
    const int bI = t >> 12, l = t & 4095;
    const int hh = l >> 6, w2 = l & 63;
    const int wi = bI * 64 + (hh >> 3) * 8 + (w2 >> 3);
    const int n  = (hh & 7) * 8 + (w2 & 7);
    row = (long)wi * 64 + n;
  } else {
    row = t;
  }
  f16x4 o4;
  o4[0] = (f16)((v0 - mu) * rs * gv.x + bv.x);
  o4[1] = (f16)((v1 - mu) * rs * gv.y + bv.y);
  o4[2] = (f16)((v2 - mu) * rs * gv.z + bv.z);
  o4[3] = (f16)((v3 - mu) * rs * gv.w + bv.w);
  *(f16x4*)(out + row * 256 + lane * 4) = o4;
}

// ---------------- GEMM: C[M,N] = A[M,K] @ Bw[N,K]^T + bias, fused epilogues ----------------
// EPI 0: f16 out = v                               (qkv)
// EPI 1: f16 out[window-reversed row] = x + v      (proj -> x1 f16), resid fp32
// EPI 2: f16 out = gelu_exact(v)                   (fc1)
// EPI 3: f32 out = x1h + v                         (fc2 + residual, final), resid f16
// f16 epilogues (0/1/2) are LDS-staged so each global store is a full-sector 16B/lane,
// 128B contiguous per row (8 lanes x f16x8).
template<int EPI, int K>
__global__ __launch_bounds__(256) void gemm_bt(
    const f16* __restrict__ A, const f16* __restrict__ Bw,
    const float* __restrict__ bias, const float* __restrict__ residf,
    const f16* __restrict__ residh,
    f16* __restrict__ outh, float* __restrict__ outf, int N) {
  __shared__ f16 As[128 * 32];
  __shared__ f16 Bs[128 * 32];
  const int tid  = threadIdx.x;
  const int wid  = tid >> 6;
  const int lane = tid & 63;
  const int qd   = lane >> 4;       // quad 0..3
  const int l16  = lane & 15;
  const long tM = (long)blockIdx.y * 128;
  const int  tN = blockIdx.x * 128;
  const int srow = lane >> 2;       // 0..15
  const int scol = (lane & 3) * 8;  // 0,8,16,24
  const int wm = (wid >> 1) * 64;
  const int wn = (wid & 1) * 64;

  f32x4 acc[4][4];
  #pragma unroll
  for (int i = 0; i < 4; ++i)
    #pragma unroll
    for (int j = 0; j < 4; ++j) acc[i][j] = (f32x4){0.f, 0.f, 0.f, 0.f};

  for (int k0 = 0; k0 < K; k0 += 32) {
    #pragma unroll
    for (int t = 0; t < 2; ++t) {
      const int gidx = wid * 2 + t;          // 16-row group 0..7
      const int row  = gidx * 16 + srow;
      __builtin_amdgcn_global_load_lds(AS1(A + (tM + row) * K + k0 + scol),
                                       AS3(&As[gidx * 512]), 16, 0, 0);
      __builtin_amdgcn_global_load_lds(AS1(Bw + (long)(tN + row) * K + k0 + scol),
                                       AS3(&Bs[gidx * 512]), 16, 0, 0);
    }
    __syncthreads();
    f16x8 af[4], bf[4];
    #pragma unroll
    for (int i = 0; i < 4; ++i) af[i] = *(const f16x8*)&As[(wm + i * 16 + l16) * 32 + qd * 8];
    #pragma unroll
    for (int j = 0; j < 4; ++j) bf[j] = *(const f16x8*)&Bs[(wn + j * 16 + l16) * 32 + qd * 8];
    #pragma unroll
    for (int i = 0; i < 4; ++i)
      #pragma unroll
      for (int j = 0; j < 4; ++j)
        acc[i][j] = __builtin_amdgcn_mfma_f32_16x16x32_f16(af[i], bf[j], acc[i][j], 0, 0, 0);
    __syncthreads();
  }

  float bb[4];
  #pragma unroll
  for (int j = 0; j < 4; ++j) bb[j] = bias[tN + wn + j * 16 + l16];

  if (EPI == 3) {
    // fp32 direct stores: 16 lanes x 4B = full 64B sectors already
    #pragma unroll
    for (int j = 0; j < 4; ++j) {
      const int col = tN + wn + j * 16 + l16;
      #pragma unroll
      for (int i = 0; i < 4; ++i) {
        #pragma unroll
        for (int r = 0; r < 4; ++r) {
          const long row = tM + wm + i * 16 + qd * 4 + r;
          const long off = row * 256 + col;
          outf[off] = (float)residh[off] + acc[i][j][r] + bb[j];
        }
      }
    }
  } else {
    // LDS-staged f16 epilogue
    f16* slice = As + wid * 1024;        // per-wave 16x64 tile (2 KB)
    const int rrow = lane >> 3;          // 0..7
    const int seg  = lane & 7;           // 0..7
    #pragma unroll
    for (int i = 0; i < 4; ++i) {
      #pragma unroll
      for (int j = 0; j < 4; ++j) {
        #pragma unroll
        for (int r = 0; r < 4; ++r) {
          float v = acc[i][j][r] + bb[j];
          if (EPI == 2) v = 0.5f * v * (1.0f + erff(v * 0.70710678118654752f));
          slice[(qd * 4 + r) * 64 + j * 16 + l16] = (f16)v;
        }
      }
      __syncthreads();
      #pragma unroll
      for (int hrow = 0; hrow < 16; hrow += 8) {
        const int lrow = hrow + rrow;                       // 0..15
        const f16x8 v8 = *(const f16x8*)(slice + lrow * 64 + seg * 8);
        const long grow = tM + wm + i * 16 + lrow;
        const int  gc   = tN + wn + seg * 8;
        if (EPI == 1) {
          const int rw = (int)grow;
          const int wi = rw >> 6, n = rw & 63;
          const int bI = wi >> 6, wloc = wi & 63;
          const int hh = (wloc >> 3) * 8 + (n >> 3);
          const int w2 = (wloc & 7) * 8 + (n & 7);
          const long prow = (long)bI * 4096 + hh * 64 + w2;
          const float* rp = residf + prow * 256 + gc;
          f16x8 o;
          #pragma unroll
          for (int k = 0; k < 8; ++k) o[k] = (f16)(rp[k] + (float)v8[k]);
          *(f16x8*)(outh + prow * 256 + gc) = o;
        } else {
          *(f16x8*)(outh + grow * N + gc) = v8;
        }
      }
      __syncthreads();
    }
  }
}

// ---------------- windowed attention: one wave per (window, head), lane = row n ----------------
__global__ __launch_bounds__(256) void attn_win(
    const f16* __restrict__ qkv, const float* __restrict__ bt,
    f16* __restrict__ out) {
  __shared__ f16 KV[4][2][64 * 32];   // per-wave K,V tiles (f16): 4 waves * 8KB
  const int wid = threadIdx.x >> 6, lane = threadIdx.x & 63;
  const int unit = blockIdx.x * 4 + wid;   // (window,head) unit within chunk
  const int wi = unit >> 3, h = unit & 7;
  const long base = (long)wi * 64 * 768;

  // stage K (cols 256+h*32..) and V (cols 512+h*32..) as 4B chunks
  #pragma unroll
  for (int i = 0; i < 16; ++i) {
    const int c = i * 64 + lane;     // 0..1023 (uint chunks; 16 per 32-elem row)
    const int row = c >> 4;
    const int cc = (c & 15) * 2;
    ((unsigned int*)KV[wid][0])[c] = *(const unsigned int*)(qkv + base + row * 768 + 256 + h * 32 + cc);
    ((unsigned int*)KV[wid][1])[c] = *(const unsigned int*)(qkv + base + row * 768 + 512 + h * 32 + cc);
  }
  __syncthreads();

  const int n = lane;
  f16x8 q8[4];
  const f16x8* qp = (const f16x8*)(qkv + base + n * 768 + h * 32);
  #pragma unroll
  for (int c = 0; c < 4; ++c) q8[c] = qp[c];

  const float scale = 0.17677669529663687f;  // 1/sqrt(32)
  float S[64];
  const f16x2* Kl = (const f16x2*)KV[wid][0];
  #pragma unroll
  for (int m = 0; m < 64; ++m) {
    float s = 0.f;
    #pragma unroll
    for (int c = 0; c < 16; ++c) {
      f16x2 qq;
      qq.x = q8[c >> 2][2 * (c & 3)];
      qq.y = q8[c >> 2][2 * (c & 3) + 1];
      s = __builtin_amdgcn_fdot2(qq, Kl[m * 16 + c], s, false);
    }
    const int idx = ((n >> 3) - (m >> 3) + 7) * 15 + ((n & 7) - (m & 7) + 7);
    S[m] = s * scale + bt[idx * 8 + h];
  }
  float mx = S[0];
  #pragma unroll
  for (int m = 1; m < 64; ++m) mx = fmaxf(mx, S[m]);

  float O[32];
  #pragma unroll
  for (int c = 0; c < 32; ++c) O[c] = 0.f;
  float sum = 0.f;
  const f16x2* Vl = (const f16x2*)KV[wid][1];
  #pragma unroll
  for (int m = 0; m < 64; ++m) {
    const float p = __expf(S[m] - mx);
    sum += p;
    #pragma unroll
    for (int c = 0; c < 16; ++c) {
      const f16x2 vv = Vl[m * 16 + c];
      O[2 * c]     += p * (float)vv.x;
      O[2 * c + 1] += p * (float)vv.y;
    }
  }
  const float inv = 1.f / sum;
  f16x8* op = (f16x8*)(out + ((long)wi * 64 + n) * 256 + h * 32);
  #pragma unroll
  for (int c8 = 0; c8 < 4; ++c8) {
    f16x8 o8;
    #pragma unroll
    for (int k = 0; k < 8; ++k) o8[k] = (f16)(O[c8 * 8 + k] * inv);
    op[c8] = o8;
  }
}

// ---------------- launch ----------------
extern "C" void kernel_launch(void* const* d_in, const int* in_sizes, int n_in,
                              void* d_out, int out_size, void* d_ws, size_t ws_size,
                              hipStream_t stream) {
  const float* x     = (const float*)d_in[0];
  const float* g1    = (const float*)d_in[2];
  const float* b1    = (const float*)d_in[3];
  const float* wqkv  = (const float*)d_in[4];
  const float* bqkv  = (const float*)d_in[5];
  const float* btab  = (const float*)d_in[6];
  const float* wproj = (const float*)d_in[7];
  const float* bproj = (const float*)d_in[8];
  const float* g2    = (const float*)d_in[9];
  const float* b2    = (const float*)d_in[10];
  const float* wfc1  = (const float*)d_in[11];
  const float* bfc1  = (const float*)d_in[12];
  const float* wfc2  = (const float*)d_in[13];
  const float* bfc2  = (const float*)d_in[14];
  float* out = (float*)d_out;

  char* ws = (char*)d_ws;
  // weights f16: 786432 elems = 1.5 MB at ws[0, 2MB)
  f16* wgt   = (f16*)ws;
  f16* wq16  = wgt;
  f16* wp16  = wgt + 196608;
  f16* wf116 = wgt + 262144;
  f16* wf216 = wgt + 524288;

  // Per-image f16 buffers: xn 2MB | qkv 6MB | x1 2MB | xn2 2MB ; h (8MB) reuses xn+qkv.
  int CH = 1;
  for (int cand = 32; cand >= 1; cand >>= 1) {
    const size_t need = 2097152ULL + (size_t)cand * 12582912ULL;
    if (need <= ws_size) { CH = cand; break; }
  }
  const int NC = 32 / CH;

  const size_t O_xn  = 2097152ULL;
  const size_t O_qkv = O_xn  + (size_t)CH * 2097152ULL;
  const size_t O_x1  = O_qkv + (size_t)CH * 6291456ULL;
  const size_t O_xn2 = O_x1  + (size_t)CH * 2097152ULL;
  f16* xnw  = (f16*)(ws + O_xn);    // ln1 out / attn out
  f16* qkvb = (f16*)(ws + O_qkv);
  f16* x1h  = (f16*)(ws + O_x1);
  f16* xn2  = (f16*)(ws + O_xn2);
  f16* hbuf = (f16*)(ws + O_xn);    // fc1 out: reuses xn+qkv (exactly CH*8MB)

  cvt_weights<<<3072, 256, 0, stream>>>(wqkv, wproj, wfc1, wfc2, wgt);

  const long imgElems = 4096L * 256;   // fp32 elems per image
  for (int c = 0; c < NC; ++c) {
    const float* xc  = x   + (long)c * CH * imgElems;
    float*       oc  = out + (long)c * CH * imgElems;
    ln_rows<true, float><<<CH * 1024, 256, 0, stream>>>(xc, g1, b1, xnw);
    gemm_bt<0, 256><<<dim3(6, CH * 32), 256, 0, stream>>>(xnw, wq16, bqkv, nullptr, nullptr, qkvb, nullptr, 768);
    attn_win<<<CH * 128, 256, 0, stream>>>(qkvb, btab, xnw);
    gemm_bt<1, 256><<<dim3(2, CH * 32), 256, 0, stream>>>(xnw, wp16, bproj, xc, nullptr, x1h, nullptr, 256);
    ln_rows<false, f16><<<CH * 1024, 256, 0, stream>>>(x1h, g2, b2, xn2);
    gemm_bt<2, 256><<<dim3(8, CH * 32), 256, 0, stream>>>(xn2, wf116, bfc1, nullptr, nullptr, hbuf, nullptr, 1024);
    gemm_bt<3, 1024><<<dim3(2, CH * 32), 256, 0, stream>>>(hbuf, wf216, bfc2, nullptr, x1h, nullptr, oc, 256);
  }
}